// Round 1
// baseline (514.771 us; speedup 1.0000x reference)
//
#include <hip/hip_runtime.h>
#include <stdint.h>
#include <math.h>

#define B_    64
#define C_    256
#define HW_   4096
#define E_    4
#define OUT_  65
#define NPAD_ 80

#define LOGITS_SZ (B_*OUT_*HW_)   /* 17,039,360 */
#define PROB_SZ   (B_*512*512)    /* 16,777,216 */

/* ws byte offsets */
#define POOLED_OFF 0u         /* 64*256 f32 = 65536 */
#define IDX_OFF    65536u     /* 64 i32 */
#define BNSUM_OFF  65792u     /* 65 f32 (pad 320) */
#define BNSS_OFF   66112u     /* 65 f32 (pad 320) */
#define SCSH_OFF   66432u     /* 65 float2 (pad 576) */
#define WT_OFF     67072u     /* 4*80*256 bf16 = 163840 */
#define YB_OFF     230912u    /* 64*65*4096 bf16 = 34,078,720 */
#define CLEAR_BYTES 66432u

typedef float  f4 __attribute__((ext_vector_type(4)));
typedef short  s8 __attribute__((ext_vector_type(8)));

__device__ __forceinline__ uint32_t f2bf(float f){
  uint32_t u = __float_as_uint(f);
  return (u + 0x7FFFu + ((u >> 16) & 1u)) >> 16;
}
__device__ __forceinline__ uint32_t pk(float lo, float hi){
  return f2bf(lo) | (f2bf(hi) << 16);
}
__device__ __forceinline__ float bf2f(uint32_t u){
  return __uint_as_float((u & 0xFFFFu) << 16);
}

/* ---------------- P1: relu + pool(sum) + transpose-to-bf16 [b][p][c] ------ */
/* grid 8192 = 64b * 4ct * 32pt ; block 256.
   thread: cg=t&7 (8 c-rows of its own), pgg=t>>3 (4 pixels). Per-thread 8x4
   register transpose -> full 128B-line reads and writes. */
__global__ __launch_bounds__(256) void k_prep(const float* __restrict__ x,
                                              uint16_t* __restrict__ xb,
                                              float* __restrict__ pooled){
  __shared__ float pool_lds[64];
  int bid = blockIdx.x;
  int b = bid >> 7, ct = (bid >> 5) & 3, pt = bid & 31;
  int t = threadIdx.x;
  int cg = t & 7, pgg = t >> 3;
  int c0 = ct*64 + cg*8;
  int p0 = pt*128 + pgg*4;
  if (t < 64) pool_lds[t] = 0.f;
  __syncthreads();

  float v[8][4]; float s[8];
  const float* xp = x + ((size_t)(b*C_ + c0))*HW_ + p0;
#pragma unroll
  for (int r = 0; r < 8; ++r){
    float4 f = *(const float4*)(xp + (size_t)r*HW_);
    v[r][0]=fmaxf(f.x,0.f); v[r][1]=fmaxf(f.y,0.f);
    v[r][2]=fmaxf(f.z,0.f); v[r][3]=fmaxf(f.w,0.f);
    s[r] = v[r][0]+v[r][1]+v[r][2]+v[r][3];
  }
  uint16_t* op = xb + ((size_t)(b*HW_ + p0))*C_ + c0;
#pragma unroll
  for (int p = 0; p < 4; ++p){
    uint4 w;
    w.x = pk(v[0][p], v[1][p]); w.y = pk(v[2][p], v[3][p]);
    w.z = pk(v[4][p], v[5][p]); w.w = pk(v[6][p], v[7][p]);
    *(uint4*)(op + (size_t)p*C_) = w;
  }
#pragma unroll
  for (int r = 0; r < 8; ++r){
    float vv = s[r];
    vv += __shfl_xor(vv, 8);
    vv += __shfl_xor(vv, 16);
    vv += __shfl_xor(vv, 32);
    if ((t & 56) == 0)                  /* one lane-set of 8 cg per wave */
      atomicAdd(&pool_lds[cg*8 + r], vv);
  }
  __syncthreads();
  if (t < 64) atomicAdd(pooled + b*C_ + ct*64 + t, pool_lds[t]);
}

/* ---------------- P2a: pack Wt[e][o][c] bf16 (pad o to 80) ---------------- */
__global__ void k_wt(const float* __restrict__ w_experts, uint16_t* __restrict__ Wt){
  int bid = blockIdx.x;
  int e = bid / OUT_, o = bid % OUT_;
  int t = threadIdx.x, c = t*4;
  const float* src = w_experts + (size_t)e*C_*OUT_ + o;
  float a0 = src[(size_t)c*OUT_],     a1 = src[(size_t)(c+1)*OUT_];
  float a2 = src[(size_t)(c+2)*OUT_], a3 = src[(size_t)(c+3)*OUT_];
  uint2 w; w.x = pk(a0,a1); w.y = pk(a2,a3);
  *(uint2*)(Wt + ((size_t)(e*NPAD_ + o))*C_ + c) = w;
}

/* ---------------- P2b: gate softmax/argmax + lb_loss ---------------------- */
__global__ void k_gate(const float* __restrict__ pooled_sum,
                       const float* __restrict__ w_gate,
                       const float* __restrict__ b_gate,
                       int* __restrict__ idx_ws, float* __restrict__ out_lb){
  __shared__ float gl[64][4];
  __shared__ int ish[64];
  int t = threadIdx.x;
  int b = t >> 2, e = t & 3;
  float dot = 0.f;
  const float* pr = pooled_sum + b*C_;
  for (int c = 0; c < C_; c += 4){
    float4 p4 = *(const float4*)(pr + c);
    dot += p4.x*w_gate[c*4+e] + p4.y*w_gate[(c+1)*4+e]
         + p4.z*w_gate[(c+2)*4+e] + p4.w*w_gate[(c+3)*4+e];
  }
  gl[b][e] = dot * (1.f/4096.f) + b_gate[e];
  __syncthreads();
  if (t < 64){
    float best = gl[t][0]; int bi = 0;
    for (int ee = 1; ee < 4; ++ee){ float vv = gl[t][ee]; if (vv > best){best = vv; bi = ee;} }
    idx_ws[t] = bi; ish[t] = bi;
  }
  __syncthreads();
  if (t == 0){
    int cnt[4] = {0,0,0,0};
    for (int bb = 0; bb < 64; ++bb) cnt[ish[bb]]++;
    double u[4], S = 0.0;
    for (int ee = 0; ee < 4; ++ee){ u[ee] = cnt[ee]/64.0 + 1e-6; S += u[ee]; }
    double lb = 0.0;
    for (int ee = 0; ee < 4; ++ee){ double uu = u[ee]/S; lb += uu*(log(uu) - log(0.25)); }
    *out_lb = (float)lb;
  }
}

/* ---------------- P3: bf16 MFMA GEMM + bias + BN partial sums ------------- */
/* grid 1024 = 64b * 16pt(256px); block 256 = 4 waves; wave: 64 px (4 Mtiles)
   x all 5 N-strips. A/B frags straight from global (A streams, B L1/L2-hot). */
__global__ __launch_bounds__(256) void k_gemm(const uint16_t* __restrict__ xb,
                                              const uint16_t* __restrict__ Wt,
                                              const int* __restrict__ idx_ws,
                                              const float* __restrict__ b_experts,
                                              uint16_t* __restrict__ yb,
                                              float* __restrict__ bnsum,
                                              float* __restrict__ bnss){
  __shared__ float2 bnp[NPAD_*4];
  int bid = blockIdx.x;
  int b = bid >> 4, pt = bid & 15;
  int t = threadIdx.x;
  int w = t >> 6, lane = t & 63;
  int l15 = lane & 15, quad = lane >> 4;
  int e = idx_ws[b];
  int p0 = pt*256 + w*64;
  const uint16_t* ap = xb + ((size_t)(b*HW_ + p0 + l15))*C_ + quad*8;
  const uint16_t* bp = Wt + (size_t)e*NPAD_*C_ + (size_t)l15*C_ + quad*8;

  f4 acc[4][5];
#pragma unroll
  for (int mt=0; mt<4; ++mt)
#pragma unroll
    for (int nt=0; nt<5; ++nt){ f4 z = {0.f,0.f,0.f,0.f}; acc[mt][nt] = z; }

#pragma unroll
  for (int ks = 0; ks < 8; ++ks){
    int ko = ks*32;
    s8 av[4], bv[5];
#pragma unroll
    for (int mt=0; mt<4; ++mt) av[mt] = *(const s8*)(ap + (size_t)mt*16*C_ + ko);
#pragma unroll
    for (int nt=0; nt<5; ++nt) bv[nt] = *(const s8*)(bp + (size_t)nt*16*C_ + ko);
#pragma unroll
    for (int mt=0; mt<4; ++mt)
#pragma unroll
      for (int nt=0; nt<5; ++nt)
        acc[mt][nt] = __builtin_amdgcn_mfma_f32_16x16x32_bf16(av[mt], bv[nt], acc[mt][nt], 0, 0, 0);
  }

#pragma unroll
  for (int nt=0; nt<5; ++nt){
    int o = nt*16 + l15;
    float bias = (o < OUT_) ? b_experts[e*OUT_ + o] : 0.f;
    float s1 = 0.f, s2 = 0.f;
#pragma unroll
    for (int mt=0; mt<4; ++mt){
#pragma unroll
      for (int r=0; r<4; ++r){
        float vv = acc[mt][nt][r] + bias;
        acc[mt][nt][r] = vv;
        s1 += vv; s2 += vv*vv;
      }
      if (o < OUT_){
        size_t base = ((size_t)(b*OUT_ + o))*HW_ + p0 + mt*16 + quad*4;
        uint2 st;
        st.x = pk(acc[mt][nt][0], acc[mt][nt][1]);
        st.y = pk(acc[mt][nt][2], acc[mt][nt][3]);
        *(uint2*)(yb + base) = st;
      }
    }
    s1 += __shfl_xor(s1, 16); s1 += __shfl_xor(s1, 32);
    s2 += __shfl_xor(s2, 16); s2 += __shfl_xor(s2, 32);
    if (quad == 0) bnp[(nt*16 + l15)*4 + w] = make_float2(s1, s2);
  }
  __syncthreads();
  if (t < OUT_){
    float2 a0 = bnp[t*4+0], a1 = bnp[t*4+1], a2 = bnp[t*4+2], a3 = bnp[t*4+3];
    atomicAdd(bnsum + t, a0.x+a1.x+a2.x+a3.x);
    atomicAdd(bnss  + t, a0.y+a1.y+a2.y+a3.y);
  }
}

/* ---------------- P4: finalize BN scale/shift ----------------------------- */
__global__ void k_stats(const float* __restrict__ bnsum, const float* __restrict__ bnss,
                        const float* __restrict__ gamma, const float* __restrict__ beta,
                        float2* __restrict__ scsh){
  int t = threadIdx.x;
  if (t < OUT_){
    const float invN = 1.f/(float)(B_*HW_);
    float mean = bnsum[t]*invN;
    float var  = bnss[t]*invN - mean*mean;
    float sc   = gamma[t] / sqrtf(var + 1e-5f);
    scsh[t] = make_float2(sc, beta[t] - mean*sc);
  }
}

/* ---------------- P5: normalize -> logits; softmax -> pixel-shuffled prob - */
/* grid 2048 = 64b * 32pt(128px); block 256. LDS tile lt[65][132]. */
__global__ __launch_bounds__(256) void k_final(const uint16_t* __restrict__ yb,
                                               const float2* __restrict__ scsh,
                                               float* __restrict__ out_logits,
                                               float* __restrict__ out_prob){
  __shared__ float lt[OUT_*132];
  __shared__ float2 ss[OUT_];
  int bid = blockIdx.x;
  int b = bid >> 5, pt = bid & 31;
  int p0 = pt*128;
  int t = threadIdx.x;
  if (t < OUT_) ss[t] = scsh[t];
  __syncthreads();

  int prr = t & 15, og = t >> 4;
#pragma unroll
  for (int oi = 0; oi < 5; ++oi){
    int o = og + oi*16;
    if (o < OUT_){
      size_t base = ((size_t)(b*OUT_ + o))*HW_ + p0 + prr*8;
      uint4 raw = *(const uint4*)(yb + base);
      float f[8];
      f[0]=bf2f(raw.x); f[1]=bf2f(raw.x>>16);
      f[2]=bf2f(raw.y); f[3]=bf2f(raw.y>>16);
      f[4]=bf2f(raw.z); f[5]=bf2f(raw.z>>16);
      f[6]=bf2f(raw.w); f[7]=bf2f(raw.w>>16);
      float2 sv = ss[o];
#pragma unroll
      for (int k=0;k<8;++k) f[k] = f[k]*sv.x + sv.y;
      float4 w0 = make_float4(f[0],f[1],f[2],f[3]);
      float4 w1 = make_float4(f[4],f[5],f[6],f[7]);
      *(float4*)(out_logits + base)     = w0;
      *(float4*)(out_logits + base + 4) = w1;
      float* lp = lt + o*132 + prr*8;
      *(float4*)(lp)     = w0;
      *(float4*)(lp + 4) = w1;
    }
  }
  __syncthreads();

  if (t < 128){
    float m = -1e30f;
    for (int o = 0; o < OUT_; ++o) m = fmaxf(m, lt[o*132 + t]);
    float ssum = 0.f;
    for (int o = 0; o < OUT_; ++o) ssum += __expf(lt[o*132 + t] - m);
    float inv = 1.f/ssum;
    int P = p0 + t;
    int h = P >> 6, wd = P & 63;
    float* pb = out_prob + ((size_t)b << 18) + (size_t)(h*8)*512 + wd*8;
#pragma unroll
    for (int r1 = 0; r1 < 8; ++r1){
      float4 q0, q1;
      q0.x = __expf(lt[(r1*8+0)*132+t]-m)*inv;
      q0.y = __expf(lt[(r1*8+1)*132+t]-m)*inv;
      q0.z = __expf(lt[(r1*8+2)*132+t]-m)*inv;
      q0.w = __expf(lt[(r1*8+3)*132+t]-m)*inv;
      q1.x = __expf(lt[(r1*8+4)*132+t]-m)*inv;
      q1.y = __expf(lt[(r1*8+5)*132+t]-m)*inv;
      q1.z = __expf(lt[(r1*8+6)*132+t]-m)*inv;
      q1.w = __expf(lt[(r1*8+7)*132+t]-m)*inv;
      *(float4*)(pb + r1*512)     = q0;
      *(float4*)(pb + r1*512 + 4) = q1;
    }
  }
}

extern "C" void kernel_launch(void* const* d_in, const int* in_sizes, int n_in,
                              void* d_out, int out_size, void* d_ws, size_t ws_size,
                              hipStream_t stream){
  const float* x         = (const float*)d_in[0];
  const float* w_experts = (const float*)d_in[1];
  const float* b_experts = (const float*)d_in[2];
  const float* w_gate    = (const float*)d_in[3];
  const float* b_gate    = (const float*)d_in[4];
  const float* gamma     = (const float*)d_in[5];
  const float* beta      = (const float*)d_in[6];

  float* out = (float*)d_out;
  char*  ws  = (char*)d_ws;
  float*     pooled = (float*)(ws + POOLED_OFF);
  int*       idxw   = (int*)(ws + IDX_OFF);
  float*     bnsum  = (float*)(ws + BNSUM_OFF);
  float*     bnss   = (float*)(ws + BNSS_OFF);
  float2*    scsh   = (float2*)(ws + SCSH_OFF);
  uint16_t*  Wt     = (uint16_t*)(ws + WT_OFF);
  uint16_t*  ybm    = (uint16_t*)(ws + YB_OFF);
  /* xb (128 MiB, bf16 [b][p][c]) lives in d_out: fully consumed by k_gemm
     before k_final overwrites d_out with logits/prob. */
  uint16_t*  xbm    = (uint16_t*)d_out;

  float* logits = out;
  float* prob   = out + LOGITS_SZ;
  float* lb     = out + LOGITS_SZ + PROB_SZ;

  hipMemsetAsync(ws, 0, CLEAR_BYTES, stream);
  k_prep <<<8192, 256, 0, stream>>>(x, xbm, pooled);
  k_wt   <<<E_*OUT_, 64, 0, stream>>>(w_experts, Wt);
  k_gate <<<1, 256, 0, stream>>>(pooled, w_gate, b_gate, idxw, lb);
  k_gemm <<<1024, 256, 0, stream>>>(xbm, Wt, idxw, b_experts, ybm, bnsum, bnss);
  k_stats<<<1, 128, 0, stream>>>(bnsum, bnss, gamma, beta, scsh);
  k_final<<<2048, 256, 0, stream>>>(ybm, scsh, logits, prob);
}

// Round 2
// 499.030 us; speedup vs baseline: 1.0315x; 1.0315x over previous
//
#include <hip/hip_runtime.h>
#include <stdint.h>
#include <math.h>

#define B_    64
#define C_    256
#define HW_   4096
#define E_    4
#define OUT_  65
#define NPAD_ 80

#define LOGITS_SZ (B_*OUT_*HW_)   /* 17,039,360 */
#define PROB_SZ   (B_*512*512)    /* 16,777,216 */

/* ws byte offsets */
#define POOLED_OFF 0u         /* 64*256 f32 = 65536 */
#define IDX_OFF    65536u     /* 64 i32 */
#define BNSUM_OFF  65792u     /* 65 f32 (pad 320) */
#define BNSS_OFF   66112u     /* 65 f32 (pad 320) */
#define WT_OFF     67072u     /* 4*5*8*64*8 bf16 = 163840 */
#define YB_OFF     230912u    /* 64*65*4096 bf16 = 34,078,720 */
#define CLEAR_BYTES 66432u

typedef float  f4 __attribute__((ext_vector_type(4)));
typedef short  s8 __attribute__((ext_vector_type(8)));

__device__ __forceinline__ uint32_t f2bf(float f){
  uint32_t u = __float_as_uint(f);
  return (u + 0x7FFFu + ((u >> 16) & 1u)) >> 16;
}
__device__ __forceinline__ uint32_t pk(float lo, float hi){
  return f2bf(lo) | (f2bf(hi) << 16);
}
__device__ __forceinline__ float bf2f(uint32_t u){
  return __uint_as_float((u & 0xFFFFu) << 16);
}

/* xb tiled layout (MFMA A-fragment order):
   elem(p, c) -> [b][T=p>>4][ks=c>>5][lane=(p&15)*4 + ((c>>3)&3)][j=c&7]
   so a GEMM wave (l15=row, quad) reads lane index l15*4+quad -> 1KB fully
   contiguous per (tile, ks) load. Wt uses the identical order per 16-o tile. */

/* ---------------- P1: relu + pool(sum) + transpose-to-bf16 tiled ---------- */
/* grid 8192 = 64b * 4ct * 32pt ; block 256.
   thread: cg=t&7 (8 c-rows), pgg=t>>3 (4 pixels). Reads: full 128B lines. */
__global__ __launch_bounds__(256) void k_prep(const float* __restrict__ x,
                                              uint16_t* __restrict__ xb,
                                              float* __restrict__ pooled){
  __shared__ float pool_lds[64];
  int bid = blockIdx.x;
  int b = bid >> 7, ct = (bid >> 5) & 3, pt = bid & 31;
  int t = threadIdx.x;
  int cg = t & 7, pgg = t >> 3;
  int c0 = ct*64 + cg*8;
  int p0 = pt*128 + pgg*4;
  if (t < 64) pool_lds[t] = 0.f;
  __syncthreads();

  float v[8][4]; float s[8];
  const float* xp = x + ((size_t)(b*C_ + c0))*HW_ + p0;
#pragma unroll
  for (int r = 0; r < 8; ++r){
    float4 f = *(const float4*)(xp + (size_t)r*HW_);
    v[r][0]=fmaxf(f.x,0.f); v[r][1]=fmaxf(f.y,0.f);
    v[r][2]=fmaxf(f.z,0.f); v[r][3]=fmaxf(f.w,0.f);
    s[r] = v[r][0]+v[r][1]+v[r][2]+v[r][3];
  }
  int ksg  = ct*2 + (cg >> 2);       /* c panel of 32 */
  int quad = cg & 3;                 /* c octet within panel */
#pragma unroll
  for (int pp = 0; pp < 4; ++pp){
    int p = p0 + pp;
    uint16_t* dst = xb + ((((size_t)(b*256 + (p>>4))*8 + ksg)*64)
                          + (size_t)((p&15)*4 + quad))*8;
    uint4 w;
    w.x = pk(v[0][pp], v[1][pp]); w.y = pk(v[2][pp], v[3][pp]);
    w.z = pk(v[4][pp], v[5][pp]); w.w = pk(v[6][pp], v[7][pp]);
    *(uint4*)dst = w;
  }
#pragma unroll
  for (int r = 0; r < 8; ++r){
    float vv = s[r];
    vv += __shfl_xor(vv, 8);
    vv += __shfl_xor(vv, 16);
    vv += __shfl_xor(vv, 32);
    if ((t & 56) == 0)
      atomicAdd(&pool_lds[cg*8 + r], vv);
  }
  __syncthreads();
  if (t < 64) atomicAdd(pooled + b*C_ + ct*64 + t, pool_lds[t]);
}

/* ---------------- P2: Wt pack (tiled, zero-padded) + gate + lb_loss ------- */
/* grid 321: blocks 0..319 = (e,o) weight pack (32 threads used);
   block 320 = gate softmax/argmax/lb. */
__global__ void k_wtgate(const float* __restrict__ w_experts,
                         const float* __restrict__ w_gate,
                         const float* __restrict__ b_gate,
                         const float* __restrict__ pooled_sum,
                         uint16_t* __restrict__ Wt,
                         int* __restrict__ idx_ws,
                         float* __restrict__ out_lb){
  int bid = blockIdx.x;
  int t = threadIdx.x;
  if (bid < 320){
    if (t >= 32) return;
    int e = bid / NPAD_, o = bid % NPAD_;
    int ks = t >> 2, quad = t & 3;
    int c = t*8;
    float a[8];
    if (o < OUT_){
      const float* src = w_experts + (size_t)e*C_*OUT_ + o;
#pragma unroll
      for (int j = 0; j < 8; ++j) a[j] = src[(size_t)(c+j)*OUT_];
    } else {
#pragma unroll
      for (int j = 0; j < 8; ++j) a[j] = 0.f;
    }
    uint4 w;
    w.x = pk(a[0],a[1]); w.y = pk(a[2],a[3]);
    w.z = pk(a[4],a[5]); w.w = pk(a[6],a[7]);
    uint16_t* dst = Wt + ((((size_t)(e*5 + (o>>4))*8 + ks)*64)
                          + (size_t)((o&15)*4 + quad))*8;
    *(uint4*)dst = w;
    return;
  }
  /* gate block */
  __shared__ float gl[64][4];
  __shared__ int ish[64];
  int b = t >> 2, e = t & 3;
  float dot = 0.f;
  const float* pr = pooled_sum + b*C_;
  for (int c = 0; c < C_; c += 4){
    float4 p4 = *(const float4*)(pr + c);
    dot += p4.x*w_gate[c*4+e] + p4.y*w_gate[(c+1)*4+e]
         + p4.z*w_gate[(c+2)*4+e] + p4.w*w_gate[(c+3)*4+e];
  }
  gl[b][e] = dot * (1.f/4096.f) + b_gate[e];
  __syncthreads();
  if (t < 64){
    float best = gl[t][0]; int bi = 0;
    for (int ee = 1; ee < 4; ++ee){ float vv = gl[t][ee]; if (vv > best){best = vv; bi = ee;} }
    idx_ws[t] = bi; ish[t] = bi;
  }
  __syncthreads();
  if (t == 0){
    int cnt[4] = {0,0,0,0};
    for (int bb = 0; bb < 64; ++bb) cnt[ish[bb]]++;
    double u[4], S = 0.0;
    for (int ee = 0; ee < 4; ++ee){ u[ee] = cnt[ee]/64.0 + 1e-6; S += u[ee]; }
    double lb = 0.0;
    for (int ee = 0; ee < 4; ++ee){ double uu = u[ee]/S; lb += uu*(log(uu) - log(0.25)); }
    *out_lb = (float)lb;
  }
}

/* ---------------- P3: bf16 MFMA GEMM + bias + BN partial sums ------------- */
/* grid 1024 = 64b * 16pt(256px); block 256 = 4 waves; wave: 64 px (4 Mtiles)
   x 5 N-strips. A/B loads are 1KB fully-contiguous per wave (tiled layout). */
__global__ __launch_bounds__(256) void k_gemm(const uint16_t* __restrict__ xb,
                                              const uint16_t* __restrict__ Wt,
                                              const int* __restrict__ idx_ws,
                                              const float* __restrict__ b_experts,
                                              uint16_t* __restrict__ yb,
                                              float* __restrict__ bnsum,
                                              float* __restrict__ bnss){
  __shared__ float2 bnp[NPAD_*4];
  int bid = blockIdx.x;
  int b = bid >> 4, pt = bid & 15;
  int t = threadIdx.x;
  int w = t >> 6, lane = t & 63;
  int l15 = lane & 15, quad = lane >> 4;
  int lid = l15*4 + quad;
  int e = idx_ws[b];
  int p0 = pt*256 + w*64;
  const uint16_t* ap = xb + ((size_t)(b*256 + pt*16 + w*4))*4096 + (size_t)lid*8;
  const uint16_t* bp = Wt + (size_t)e*5*4096 + (size_t)lid*8;

  f4 acc[4][5];
#pragma unroll
  for (int mt=0; mt<4; ++mt)
#pragma unroll
    for (int nt=0; nt<5; ++nt){ f4 z = {0.f,0.f,0.f,0.f}; acc[mt][nt] = z; }

#pragma unroll
  for (int ks = 0; ks < 8; ++ks){
    s8 av[4], bv[5];
#pragma unroll
    for (int mt=0; mt<4; ++mt) av[mt] = *(const s8*)(ap + (size_t)mt*4096 + ks*512);
#pragma unroll
    for (int nt=0; nt<5; ++nt) bv[nt] = *(const s8*)(bp + (size_t)nt*4096 + ks*512);
#pragma unroll
    for (int mt=0; mt<4; ++mt)
#pragma unroll
      for (int nt=0; nt<5; ++nt)
        acc[mt][nt] = __builtin_amdgcn_mfma_f32_16x16x32_bf16(av[mt], bv[nt], acc[mt][nt], 0, 0, 0);
  }

#pragma unroll
  for (int nt=0; nt<5; ++nt){
    int o = nt*16 + l15;
    float bias = (o < OUT_) ? b_experts[e*OUT_ + o] : 0.f;
    float s1 = 0.f, s2 = 0.f;
#pragma unroll
    for (int mt=0; mt<4; ++mt){
#pragma unroll
      for (int r=0; r<4; ++r){
        float vv = acc[mt][nt][r] + bias;
        acc[mt][nt][r] = vv;
        s1 += vv; s2 += vv*vv;
      }
      if (o < OUT_){
        size_t base = ((size_t)(b*OUT_ + o))*HW_ + p0 + mt*16 + quad*4;
        uint2 st;
        st.x = pk(acc[mt][nt][0], acc[mt][nt][1]);
        st.y = pk(acc[mt][nt][2], acc[mt][nt][3]);
        *(uint2*)(yb + base) = st;
      }
    }
    s1 += __shfl_xor(s1, 16); s1 += __shfl_xor(s1, 32);
    s2 += __shfl_xor(s2, 16); s2 += __shfl_xor(s2, 32);
    if (quad == 0) bnp[(nt*16 + l15)*4 + w] = make_float2(s1, s2);
  }
  __syncthreads();
  if (t < OUT_){
    float2 a0 = bnp[t*4+0], a1 = bnp[t*4+1], a2 = bnp[t*4+2], a3 = bnp[t*4+3];
    atomicAdd(bnsum + t, a0.x+a1.x+a2.x+a3.x);
    atomicAdd(bnss  + t, a0.y+a1.y+a2.y+a3.y);
  }
}

/* ---------------- P4: BN finalize (per-block) + logits + softmax + shuffle  */
/* grid 2048 = 64b * 32pt(128px); block 256. LDS tile lt[65][132]. */
__global__ __launch_bounds__(256) void k_final(const uint16_t* __restrict__ yb,
                                               const float* __restrict__ bnsum,
                                               const float* __restrict__ bnss,
                                               const float* __restrict__ gamma,
                                               const float* __restrict__ beta,
                                               float* __restrict__ out_logits,
                                               float* __restrict__ out_prob){
  __shared__ float lt[OUT_*132];
  __shared__ float2 ss[OUT_];
  int bid = blockIdx.x;
  int b = bid >> 5, pt = bid & 31;
  int p0 = pt*128;
  int t = threadIdx.x;
  if (t < OUT_){
    const float invN = 1.f/(float)(B_*HW_);
    float mean = bnsum[t]*invN;
    float var  = bnss[t]*invN - mean*mean;
    float sc   = gamma[t] / sqrtf(var + 1e-5f);
    ss[t] = make_float2(sc, beta[t] - mean*sc);
  }
  __syncthreads();

  int prr = t & 15, og = t >> 4;
#pragma unroll
  for (int oi = 0; oi < 5; ++oi){
    int o = og + oi*16;
    if (o < OUT_){
      size_t base = ((size_t)(b*OUT_ + o))*HW_ + p0 + prr*8;
      uint4 raw = *(const uint4*)(yb + base);
      float f[8];
      f[0]=bf2f(raw.x); f[1]=bf2f(raw.x>>16);
      f[2]=bf2f(raw.y); f[3]=bf2f(raw.y>>16);
      f[4]=bf2f(raw.z); f[5]=bf2f(raw.z>>16);
      f[6]=bf2f(raw.w); f[7]=bf2f(raw.w>>16);
      float2 sv = ss[o];
#pragma unroll
      for (int k=0;k<8;++k) f[k] = f[k]*sv.x + sv.y;
      float4 w0 = make_float4(f[0],f[1],f[2],f[3]);
      float4 w1 = make_float4(f[4],f[5],f[6],f[7]);
      *(float4*)(out_logits + base)     = w0;
      *(float4*)(out_logits + base + 4) = w1;
      float* lp = lt + o*132 + prr*8;
      *(float4*)(lp)     = w0;
      *(float4*)(lp + 4) = w1;
    }
  }
  __syncthreads();

  if (t < 128){
    float m = -1e30f;
    for (int o = 0; o < OUT_; ++o) m = fmaxf(m, lt[o*132 + t]);
    float ssum = 0.f;
    for (int o = 0; o < OUT_; ++o) ssum += __expf(lt[o*132 + t] - m);
    float inv = 1.f/ssum;
    int P = p0 + t;
    int h = P >> 6, wd = P & 63;
    float* pb = out_prob + ((size_t)b << 18) + (size_t)(h*8)*512 + wd*8;
#pragma unroll
    for (int r1 = 0; r1 < 8; ++r1){
      float4 q0, q1;
      q0.x = __expf(lt[(r1*8+0)*132+t]-m)*inv;
      q0.y = __expf(lt[(r1*8+1)*132+t]-m)*inv;
      q0.z = __expf(lt[(r1*8+2)*132+t]-m)*inv;
      q0.w = __expf(lt[(r1*8+3)*132+t]-m)*inv;
      q1.x = __expf(lt[(r1*8+4)*132+t]-m)*inv;
      q1.y = __expf(lt[(r1*8+5)*132+t]-m)*inv;
      q1.z = __expf(lt[(r1*8+6)*132+t]-m)*inv;
      q1.w = __expf(lt[(r1*8+7)*132+t]-m)*inv;
      *(float4*)(pb + r1*512)     = q0;
      *(float4*)(pb + r1*512 + 4) = q1;
    }
  }
}

extern "C" void kernel_launch(void* const* d_in, const int* in_sizes, int n_in,
                              void* d_out, int out_size, void* d_ws, size_t ws_size,
                              hipStream_t stream){
  const float* x         = (const float*)d_in[0];
  const float* w_experts = (const float*)d_in[1];
  const float* b_experts = (const float*)d_in[2];
  const float* w_gate    = (const float*)d_in[3];
  const float* b_gate    = (const float*)d_in[4];
  const float* gamma     = (const float*)d_in[5];
  const float* beta      = (const float*)d_in[6];

  float* out = (float*)d_out;
  char*  ws  = (char*)d_ws;
  float*     pooled = (float*)(ws + POOLED_OFF);
  int*       idxw   = (int*)(ws + IDX_OFF);
  float*     bnsum  = (float*)(ws + BNSUM_OFF);
  float*     bnss   = (float*)(ws + BNSS_OFF);
  uint16_t*  Wt     = (uint16_t*)(ws + WT_OFF);
  uint16_t*  ybm    = (uint16_t*)(ws + YB_OFF);
  /* xb (128 MiB, bf16 tiled) lives in d_out: fully consumed by k_gemm
     before k_final overwrites d_out with logits/prob. */
  uint16_t*  xbm    = (uint16_t*)d_out;

  float* logits = out;
  float* prob   = out + LOGITS_SZ;
  float* lb     = out + LOGITS_SZ + PROB_SZ;

  hipMemsetAsync(ws, 0, CLEAR_BYTES, stream);
  k_prep  <<<8192, 256, 0, stream>>>(x, xbm, pooled);
  k_wtgate<<<321, 256, 0, stream>>>(w_experts, w_gate, b_gate, pooled, Wt, idxw, lb);
  k_gemm  <<<1024, 256, 0, stream>>>(xbm, Wt, idxw, b_experts, ybm, bnsum, bnss);
  k_final <<<2048, 256, 0, stream>>>(ybm, bnsum, bnss, gamma, beta, logits, prob);
}